// Round 18
// baseline (374.397 us; speedup 1.0000x reference)
//
#include <hip/hip_runtime.h>
#include <hip/hip_bf16.h>

#define NN 20000
#define EE 320000
#define RR 8
#define NR (NN * RR)
#define NB 40     // scan blocks per graph: ceil(160000/4096)
#define SCAP 640  // LDS edge-window capacity for 32 rows (mean 512, sd ~23)

typedef float f32x4 __attribute__((ext_vector_type(4)));
typedef float f32x2 __attribute__((ext_vector_type(2)));
typedef short s16x8 __attribute__((ext_vector_type(8)));

__device__ __forceinline__ unsigned short f2bf(float f) {
  unsigned u = __builtin_bit_cast(unsigned, f);
  unsigned r = u + 0x7FFFu + ((u >> 16) & 1u);
  return (unsigned short)(r >> 16);
}
// (lo, hi) of a packed bf16 pair as exact f32 values
__device__ __forceinline__ f32x2 bf2x2(unsigned u) {
  f32x2 r;
  r.x = __builtin_bit_cast(float, u << 16);
  r.y = __builtin_bit_cast(float, u & 0xFFFF0000u);
  return r;
}
__device__ __forceinline__ void gload_lds16(const void* g, void* l) {
  __builtin_amdgcn_global_load_lds(
      (const __attribute__((address_space(1))) unsigned*)g,
      (__attribute__((address_space(3))) unsigned*)l, 16, 0, 0);
}

// ---- per-(graph,dst,relation) segment count, both graphs ----
__global__ void k_count(const int* __restrict__ ei, const int* __restrict__ et,
                        int* __restrict__ cnt) {
  int e = blockIdx.x * blockDim.x + threadIdx.x;  // 0..2*EE
  int g = e >= EE;
  int el = e - g * EE;
  int d = ei[(size_t)g * 2 * EE + EE + el];
  int t = et[(size_t)g * EE + el];
  atomicAdd(&cnt[(size_t)g * NR + d * RR + t], 1);
}

// ---- hierarchical exclusive scan ----
__global__ __launch_bounds__(1024) void k_scan1(const int* __restrict__ cnt,
                                                int* __restrict__ off,
                                                int* __restrict__ btot) {
  int g = blockIdx.y, b = blockIdx.x;
  const int* c = cnt + (size_t)g * NR;
  int* o = off + (size_t)g * NR;
  __shared__ int wsum[16];
  int lane = threadIdx.x & 63, w = threadIdx.x >> 6;
  int i = b * 4096 + (int)threadIdx.x * 4;
  int4 v = {0, 0, 0, 0};
  if (i + 3 < NR) v = *(const int4*)&c[i];
  else {
    if (i < NR) v.x = c[i];
    if (i + 1 < NR) v.y = c[i + 1];
    if (i + 2 < NR) v.z = c[i + 2];
  }
  int s0 = v.x, s1 = s0 + v.y, s2 = s1 + v.z, s3 = s2 + v.w;
  int s = s3;
  for (int d = 1; d < 64; d <<= 1) {
    int t = __shfl_up(s, d);
    if (lane >= d) s += t;
  }
  if (lane == 63) wsum[w] = s;
  __syncthreads();
  if (threadIdx.x < 16) {
    int ws = wsum[threadIdx.x];
    for (int d = 1; d < 16; d <<= 1) {
      int t = __shfl_up(ws, d);
      if ((int)threadIdx.x >= d) ws += t;
    }
    wsum[threadIdx.x] = ws;
  }
  __syncthreads();
  int excl = (w > 0 ? wsum[w - 1] : 0) + (s - s3);
  if (i < NR) o[i] = excl;
  if (i + 1 < NR) o[i + 1] = excl + s0;
  if (i + 2 < NR) o[i + 2] = excl + s1;
  if (i + 3 < NR) o[i + 3] = excl + s2;
  if (threadIdx.x == 0) btot[g * NB + b] = wsum[15];
}

__global__ void k_scan2(const int* __restrict__ btot, int* __restrict__ bof) {
  int g = threadIdx.x >> 6, lane = threadIdx.x & 63;
  int v = (lane < NB) ? btot[g * NB + lane] : 0;
  int s = v;
  for (int d = 1; d < 64; d <<= 1) {
    int t = __shfl_up(s, d);
    if (lane >= d) s += t;
  }
  if (lane < NB) bof[g * NB + lane] = s - v;
}

__global__ __launch_bounds__(1024) void k_scan3(int* __restrict__ off,
                                                const int* __restrict__ bof) {
  int g = blockIdx.y;
  int add = bof[g * NB + blockIdx.x];
  int i = blockIdx.x * 4096 + (int)threadIdx.x * 4;
  int* o = off + (size_t)g * NR;
  if (i + 3 < NR) {
    int4 v = *(const int4*)&o[i];
    v.x += add; v.y += add; v.z += add; v.w += add;
    *(int4*)&o[i] = v;
  } else {
    for (int j = i; j < NR; ++j) o[j] += add;
  }
}

// ---- scatter src ids; DESTROYS off: post-scatter off[s] = end of segment s ----
__global__ void k_scatter(const int* __restrict__ ei, const int* __restrict__ et,
                          int* __restrict__ off, int* __restrict__ ssrc) {
  int e = blockIdx.x * blockDim.x + threadIdx.x;
  int g = e >= EE;
  int el = e - g * EE;
  int s = ei[(size_t)g * 2 * EE + el];
  int d = ei[(size_t)g * 2 * EE + EE + el];
  int t = et[(size_t)g * EE + el];
  int pos = atomicAdd(&off[(size_t)g * NR + d * RR + t], 1);
  ssrc[(size_t)g * EE + pos] = s;
}

// ---- fp32 x -> bf16, both graphs, into per-graph NN*256-strided slots ----
__global__ void k_cvt(const float* __restrict__ x, unsigned short* __restrict__ hX) {
  int i = (blockIdx.x * blockDim.x + threadIdx.x) * 4;
  if (i >= 2 * NN * 128) return;
  int g = i >= NN * 128;
  int il = i - g * NN * 128;
  float4 v = *(const float4*)&x[i];
  ushort4 o;
  o.x = f2bf(v.x); o.y = f2bf(v.y); o.z = f2bf(v.z); o.w = f2bf(v.w);
  *(ushort4*)&hX[(size_t)g * NN * 256 + il] = o;
}

// ---- fragment-ordered bf16 weight panel:
// btf[((s*(Cout/16)+fr)*2+kk)*512 + lane*8 + j] = BT[co][k]
//   co = fr*16 + (lane&15);  k = s*64 + kk*32 + (lane>>4)*8 + j  (r=8 -> root)
__global__ void k_btf(const float* __restrict__ W, const float* __restrict__ root,
                      unsigned short* __restrict__ btf, int Cin, int Cout,
                      int Ktot) {
  int idx = blockIdx.x * blockDim.x + threadIdx.x;
  if (idx >= Cout * Ktot) return;
  int j = idx & 7;
  int lane = (idx >> 3) & 63;
  int kk = (idx >> 9) & 1;
  int t = idx >> 10;  // s*(Cout/16) + fr
  int fr = t % (Cout / 16);
  int s = t / (Cout / 16);
  int co = fr * 16 + (lane & 15);
  int k = s * 64 + kk * 32 + (lane >> 4) * 8 + j;
  int r = k / Cin, ci = k - r * Cin;
  float v = (r < RR) ? W[((size_t)r * Cin + ci) * Cout + co]
                     : root[(size_t)ci * Cout + co];
  btf[idx] = f2bf(v);
}

// coalesced B-frag load for step s: per (kk,f) 64 lanes read contiguous 1KB
#define LOADB(bb, s)                                                           \
  _Pragma("unroll") for (int kk = 0; kk < 2; ++kk)                             \
      _Pragma("unroll") for (int f = 0; f < 4; ++f) bb[kk][f] =                \
          *(const s16x8*)(btl +                                                \
                          (size_t)(((s) * (COUT / 16) + wn16 + f) * 2 + kk) *  \
                              512);

// MFMA over sub-tile j of As with B regs bb
#define MFMA_STEP_C(j, bb)                                                     \
  do {                                                                         \
    __builtin_amdgcn_s_setprio(1);                                             \
    _Pragma("unroll") for (int kk = 0; kk < 2; ++kk) {                         \
      s16x8 a[MF];                                                             \
      _Pragma("unroll") for (int f = 0; f < MF; ++f) {                         \
        int row = wm + f * 16 + (lane & 15);                                   \
        int colb = kk * 64 + (lane >> 4) * 16;                                 \
        a[f] = *(const s16x8*)(As + (j)*ASTR + row * 128 +                     \
                               (colb ^ ((row & 7) << 4)));                     \
      }                                                                        \
      _Pragma("unroll") for (int fm = 0; fm < MF; ++fm)                        \
          _Pragma("unroll") for (int fn = 0; fn < 4; ++fn)                     \
              acc[fm][fn] = __builtin_amdgcn_mfma_f32_16x16x32_bf16(           \
                  a[fm], bb[kk][fn], acc[fm][fn], 0, 0, 0);                    \
    }                                                                          \
    __builtin_amdgcn_s_setprio(0);                                             \
  } while (0)

// accumulate one uint4 (8 bf16) into packed float2 banks (v_pk_add_f32)
#define ACC4(u)                                                                \
  {                                                                            \
    fa2[c][0] += bf2x2((u).x);                                                 \
    fa2[c][1] += bf2x2((u).y);                                                 \
    fa2[c][2] += bf2x2((u).z);                                                 \
    fa2[c][3] += bf2x2((u).w);                                                 \
  }

// ---- fused gather+GEMM, 32-row x COUT tile, RPP relations per phase
// (RPP*CH == 8 sub-tiles), packed-f32 walk, B in registers with 3-deep
// static rotation (bA/bB/bC) + prefetch-under-produce ----
template <int CIN, int COUT, bool OUTF32>
__global__ __launch_bounds__(256) void k_fused(
    const int* __restrict__ ssrc, const int* __restrict__ off,
    const unsigned short* __restrict__ h, const unsigned short* __restrict__ btf,
    const float* __restrict__ bias, void* __restrict__ outp) {
  constexpr int KTOT = (RR + 1) * CIN;
  constexpr int NS = KTOT / 64;    // flat K-steps (18 or 36)
  constexpr int CH = CIN / 64;     // sub-tiles per relation (2 or 4)
  constexpr int RPP = 8 / CH;      // relations per phase (4 or 2)
  constexpr int NPH = RR / RPP;    // phases (2 or 4)
  constexpr int CPT = CIN / 8;     // cols per thread in walk (16 or 32)
  constexpr int NCH = CPT / 8;     // 16B chunks per thread (2 or 4)
  constexpr int NWN = COUT / 64;   // n-waves (4 or 2)
  constexpr int MW = 4 / NWN;      // m-waves (1 or 2)
  constexpr int WR = 32 / MW;      // rows per wave (32 or 16)
  constexpr int MF = WR / 16;      // m-frags per wave (2 or 1)
  constexpr int ASTR = 4112;       // padded sub-tile stride (4096+16, not %128)
  constexpr int SH = (CIN == 256) ? 9 : 8;  // src -> h-row byte offset shift
  static_assert(RPP * CH == 8, "phase holds 8 sub-tiles");
  __shared__ char As[8 * ASTR];    // one phase's sub-tiles
  __shared__ int offs[32][9];      // per-row segment boundaries (start + 8 ends)
  __shared__ int sseg[SCAP];       // this block's edge window (BYTE offsets)
  const int tid = threadIdx.x, lane = tid & 63, wave = tid >> 6;
  const int wn = (wave % NWN) * 64;
  const int wn16 = wn >> 4;
  const int wm = (wave / NWN) * WR;
  const int m0 = blockIdx.x * 32;  // NN == 625*32, no clamps needed
  const int g = blockIdx.z;
  ssrc += (size_t)g * EE;
  off += (size_t)g * NR;
  h += (size_t)g * NN * 256;

  for (int idx = tid; idx < 32 * 9; idx += 256) {
    int row = idx / 9, j = idx - row * 9;
    int seg0 = (m0 + row) * RR;
    offs[row][j] = (j == 0) ? (seg0 == 0 ? 0 : off[seg0 - 1]) : off[seg0 + j - 1];
  }
  const int segA = m0 * RR;
  const int ebase = (segA == 0) ? 0 : off[segA - 1];
  const int eend = off[(m0 + 32) * RR - 1];
  const int cntE = eend - ebase;
  const bool inl = cntE <= SCAP;
  if (inl)
    for (int i = tid; i < cntE; i += 256) sseg[i] = ssrc[ebase + i] << SH;
  __syncthreads();

  f32x4 acc[MF][4] = {};
  const int arow = tid >> 3;              // this thread's A row (0..31)
  const int q = tid & 7;                  // 8 threads/row, CPT cols each
  const int swzA = (arow & 7) << 4;
  const char* hqB = (const char*)h + (size_t)q * CPT * 2;
  const unsigned short* btl = btf + lane * 8;

  // walk relation r's segment; write means into sub-tile base (r%RPP)*CH
  auto produce = [&](int r) {
    f32x2 fa2[NCH][4];
#pragma unroll
    for (int c = 0; c < NCH; ++c)
#pragma unroll
      for (int w = 0; w < 4; ++w) fa2[c][w] = (f32x2)(0.f);
    const int o0 = offs[arow][r], o1 = offs[arow][r + 1];
    if (inl) {  // hot path: edge ids (pre-shifted byte offsets) in LDS
      int e = o0 - ebase;
      const int e1 = o1 - ebase;
      for (; e + 1 < e1; e += 2) {
        const unsigned short* pa = (const unsigned short*)(hqB + sseg[e]);
        const unsigned short* pb = (const unsigned short*)(hqB + sseg[e + 1]);
#pragma unroll
        for (int c = 0; c < NCH; ++c) {
          uint4 ua = *(const uint4*)(pa + c * 8);
          uint4 ub = *(const uint4*)(pb + c * 8);
          ACC4(ua);
          ACC4(ub);
        }
      }
      if (e < e1) {
        const unsigned short* pa = (const unsigned short*)(hqB + sseg[e]);
#pragma unroll
        for (int c = 0; c < NCH; ++c) {
          uint4 ua = *(const uint4*)(pa + c * 8);
          ACC4(ua);
        }
      }
    } else {  // cold fallback: window overflow, read ids from global
      for (int e = o0; e < o1; ++e) {
        const unsigned short* pa = (const unsigned short*)(hqB + (ssrc[e] << SH));
#pragma unroll
        for (int c = 0; c < NCH; ++c) {
          uint4 ua = *(const uint4*)(pa + c * 8);
          ACC4(ua);
        }
      }
    }
    float inv = 1.0f / fmaxf((float)(o1 - o0), 1.0f);
    char* half = As + (r % RPP) * (CH * ASTR);
#pragma unroll
    for (int c = 0; c < NCH; ++c) {
      s16x8 mbv;
#pragma unroll
      for (int w = 0; w < 4; ++w) {
        mbv[2 * w] = (short)f2bf(fa2[c][w].x * inv);
        mbv[2 * w + 1] = (short)f2bf(fa2[c][w].y * inv);
      }
      int colb = (q * CPT + c * 8) * 2;  // byte col in full CIN row
      int ct = colb >> 7;                // sub-tile index within relation
      int wb = colb & 127;               // byte within 128-B window
      *(s16x8*)(half + ct * ASTR + arow * 128 + (wb ^ swzA)) = mbv;
    }
  };

  // root term: stage h rows into sub-tiles 0..CH-1 via global_load_lds
  auto root_stage = [&]() {
#pragma unroll
    for (int i = 0; i < CH; ++i) {
      int o = i * ASTR + wave * 1024;  // wave-uniform LDS base
      int ob = wave * 1024 + lane * 16;
      int row = (ob >> 7) & 31;
      int wb = ob & 127;
      gload_lds16((const char*)h + ((size_t)(m0 + row) * CIN + i * 64) * 2 +
                      (wb ^ ((row & 7) << 4)),
                  As + o);
    }
  };

  s16x8 bA[2][4], bB[2][4], bC[2][4];
  LOADB(bA, 0);   // complete by first barrier (drains vmcnt)
  LOADB(bB, 1);
#pragma unroll
  for (int r0 = 0; r0 < RPP; ++r0) produce(r0);
  __syncthreads();

  for (int p = 0; p < NPH; ++p) {
    const int s0 = p * 8;
    // 8 steps, 3-set static rotation: 2-step B lookahead throughout
    LOADB(bC, s0 + 2); MFMA_STEP_C(0, bA);
    LOADB(bA, s0 + 3); MFMA_STEP_C(1, bB);
    LOADB(bB, s0 + 4); MFMA_STEP_C(2, bC);
    LOADB(bC, s0 + 5); MFMA_STEP_C(3, bA);
    LOADB(bA, s0 + 6); MFMA_STEP_C(4, bB);
    LOADB(bB, s0 + 7); MFMA_STEP_C(5, bC);
    MFMA_STEP_C(6, bA);
    MFMA_STEP_C(7, bB);
    __syncthreads();  // all waves done reading As
    // prefetch next phase's (or root's) first two B sets; they complete
    // under the produce/root_stage work below (barrier drains vmcnt anyway)
    LOADB(bA, s0 + 8);      // s0+8 <= RR*CH < NS
    LOADB(bB, s0 + 9);      // s0+9 <= RR*CH+1 < NS (CH >= 2)
    if (p < NPH - 1) {
#pragma unroll
      for (int r0 = 0; r0 < RPP; ++r0) produce((p + 1) * RPP + r0);
    } else {
      root_stage();
    }
    __syncthreads();  // As writes visible
  }
  // root MFMA phase: steps RR*CH .. NS-1 (CH steps); bA,bB preloaded
  {
    constexpr int s0r = RR * CH;
    if constexpr (CH == 4) {
      LOADB(bC, s0r + 2);
      MFMA_STEP_C(0, bA);
      LOADB(bA, s0r + 3);
      MFMA_STEP_C(1, bB);
      MFMA_STEP_C(2, bC);
      MFMA_STEP_C(3, bA);
    } else {
      MFMA_STEP_C(0, bA);
      MFMA_STEP_C(1, bB);
    }
  }

  // ---- epilogue: bias + LeakyReLU ----
#pragma unroll
  for (int fm = 0; fm < MF; ++fm) {
    int rbase = m0 + wm + fm * 16 + (lane >> 4) * 4;
#pragma unroll
    for (int fn = 0; fn < 4; ++fn) {
      int col = wn + fn * 16 + (lane & 15);
      float bv = bias[col];
#pragma unroll
      for (int v = 0; v < 4; ++v) {
        int row = rbase + v;
        float xv = acc[fm][fn][v] + bv;
        xv = xv > 0.f ? xv : 0.2f * xv;
        if constexpr (OUTF32)
          ((float*)outp)[(size_t)g * NN * COUT + (size_t)row * COUT + col] = xv;
        else
          ((unsigned short*)outp)[(size_t)g * NN * 256 + (size_t)row * COUT +
                                  col] = f2bf(xv);
      }
    }
  }
}

extern "C" void kernel_launch(void* const* d_in, const int* in_sizes, int n_in,
                              void* d_out, int out_size, void* d_ws, size_t ws_size,
                              hipStream_t stream) {
  const float* x  = (const float*)d_in[0];
  const int* ei   = (const int*)d_in[1];
  const int* etp  = (const int*)d_in[2];
  const float* W0 = (const float*)d_in[3];
  const float* r0 = (const float*)d_in[4];
  const float* b0 = (const float*)d_in[5];
  const float* W1 = (const float*)d_in[6];
  const float* r1 = (const float*)d_in[7];
  const float* b1 = (const float*)d_in[8];
  const float* W2 = (const float*)d_in[9];
  const float* r2 = (const float*)d_in[10];
  const float* b2 = (const float*)d_in[11];

  char* p = (char*)d_ws;
  unsigned short* hX  = (unsigned short*)p; p += (size_t)2 * NN * 256 * 2;
  unsigned short* h_a = (unsigned short*)p; p += (size_t)2 * NN * 256 * 2;
  int* cnt  = (int*)p; p += (size_t)2 * NR * 4;
  int* off  = (int*)p; p += (size_t)2 * NR * 4;
  int* btot = (int*)p; p += (size_t)2 * NB * 4;
  int* bof  = (int*)p; p += (size_t)2 * NB * 4;
  int* ssrc = (int*)p; p += (size_t)2 * EE * 4;
  unsigned short* bt0 = (unsigned short*)p; p += (size_t)256 * 1152 * 2;
  unsigned short* bt1 = (unsigned short*)p; p += (size_t)256 * 2304 * 2;
  unsigned short* bt2 = (unsigned short*)p; p += (size_t)128 * 2304 * 2;

  // fragment-ordered weight panels (graph-independent)
  k_btf<<<(256 * 1152 + 255) / 256, 256, 0, stream>>>(W0, r0, bt0, 128, 256, 1152);
  k_btf<<<(256 * 2304 + 255) / 256, 256, 0, stream>>>(W1, r1, bt1, 256, 256, 2304);
  k_btf<<<(128 * 2304 + 255) / 256, 256, 0, stream>>>(W2, r2, bt2, 256, 128, 2304);

  // edge sort (both graphs batched)
  (void)hipMemsetAsync(cnt, 0, (size_t)2 * NR * 4, stream);
  k_count<<<2 * EE / 256, 256, 0, stream>>>(ei, etp, cnt);
  k_scan1<<<dim3(NB, 2), 1024, 0, stream>>>(cnt, off, btot);
  k_scan2<<<1, 128, 0, stream>>>(btot, bof);
  k_scan3<<<dim3(NB, 2), 1024, 0, stream>>>(off, bof);
  k_cvt<<<2 * NN * 128 / 4 / 256, 256, 0, stream>>>(x, hX);
  k_scatter<<<2 * EE / 256, 256, 0, stream>>>(ei, etp, off, ssrc);

  // layer 0: 128 -> 256 (fused gather+GEMM)
  k_fused<128, 256, false><<<dim3(625, 1, 2), 256, 0, stream>>>(
      ssrc, off, hX, bt0, b0, h_a);
  // layer 1: 256 -> 256
  k_fused<256, 256, false><<<dim3(625, 1, 2), 256, 0, stream>>>(
      ssrc, off, h_a, bt1, b1, hX);
  // layer 2: 256 -> 128
  k_fused<256, 128, true><<<dim3(625, 1, 2), 256, 0, stream>>>(
      ssrc, off, hX, bt2, b2, d_out);
}

// Round 19
// 343.589 us; speedup vs baseline: 1.0897x; 1.0897x over previous
//
#include <hip/hip_runtime.h>
#include <hip/hip_bf16.h>

#define NN 20000
#define EE 320000
#define RR 8
#define NR (NN * RR)
#define NB 40     // scan blocks per graph: ceil(160000/4096)
#define SCAP 640  // LDS edge-window capacity for 32 rows (mean 512, sd ~23)

typedef float f32x4 __attribute__((ext_vector_type(4)));
typedef float f32x2 __attribute__((ext_vector_type(2)));
typedef short s16x8 __attribute__((ext_vector_type(8)));

__device__ __forceinline__ unsigned short f2bf(float f) {
  unsigned u = __builtin_bit_cast(unsigned, f);
  unsigned r = u + 0x7FFFu + ((u >> 16) & 1u);
  return (unsigned short)(r >> 16);
}
// (lo, hi) of a packed bf16 pair as exact f32 values
__device__ __forceinline__ f32x2 bf2x2(unsigned u) {
  f32x2 r;
  r.x = __builtin_bit_cast(float, u << 16);
  r.y = __builtin_bit_cast(float, u & 0xFFFF0000u);
  return r;
}
__device__ __forceinline__ void gload_lds16(const void* g, void* l) {
  __builtin_amdgcn_global_load_lds(
      (const __attribute__((address_space(1))) unsigned*)g,
      (__attribute__((address_space(3))) unsigned*)l, 16, 0, 0);
}

// ---- per-(graph,dst,relation) segment count, both graphs ----
__global__ void k_count(const int* __restrict__ ei, const int* __restrict__ et,
                        int* __restrict__ cnt) {
  int e = blockIdx.x * blockDim.x + threadIdx.x;  // 0..2*EE
  int g = e >= EE;
  int el = e - g * EE;
  int d = ei[(size_t)g * 2 * EE + EE + el];
  int t = et[(size_t)g * EE + el];
  atomicAdd(&cnt[(size_t)g * NR + d * RR + t], 1);
}

// ---- hierarchical exclusive scan ----
__global__ __launch_bounds__(1024) void k_scan1(const int* __restrict__ cnt,
                                                int* __restrict__ off,
                                                int* __restrict__ btot) {
  int g = blockIdx.y, b = blockIdx.x;
  const int* c = cnt + (size_t)g * NR;
  int* o = off + (size_t)g * NR;
  __shared__ int wsum[16];
  int lane = threadIdx.x & 63, w = threadIdx.x >> 6;
  int i = b * 4096 + (int)threadIdx.x * 4;
  int4 v = {0, 0, 0, 0};
  if (i + 3 < NR) v = *(const int4*)&c[i];
  else {
    if (i < NR) v.x = c[i];
    if (i + 1 < NR) v.y = c[i + 1];
    if (i + 2 < NR) v.z = c[i + 2];
  }
  int s0 = v.x, s1 = s0 + v.y, s2 = s1 + v.z, s3 = s2 + v.w;
  int s = s3;
  for (int d = 1; d < 64; d <<= 1) {
    int t = __shfl_up(s, d);
    if (lane >= d) s += t;
  }
  if (lane == 63) wsum[w] = s;
  __syncthreads();
  if (threadIdx.x < 16) {
    int ws = wsum[threadIdx.x];
    for (int d = 1; d < 16; d <<= 1) {
      int t = __shfl_up(ws, d);
      if ((int)threadIdx.x >= d) ws += t;
    }
    wsum[threadIdx.x] = ws;
  }
  __syncthreads();
  int excl = (w > 0 ? wsum[w - 1] : 0) + (s - s3);
  if (i < NR) o[i] = excl;
  if (i + 1 < NR) o[i + 1] = excl + s0;
  if (i + 2 < NR) o[i + 2] = excl + s1;
  if (i + 3 < NR) o[i + 3] = excl + s2;
  if (threadIdx.x == 0) btot[g * NB + b] = wsum[15];
}

__global__ void k_scan2(const int* __restrict__ btot, int* __restrict__ bof) {
  int g = threadIdx.x >> 6, lane = threadIdx.x & 63;
  int v = (lane < NB) ? btot[g * NB + lane] : 0;
  int s = v;
  for (int d = 1; d < 64; d <<= 1) {
    int t = __shfl_up(s, d);
    if (lane >= d) s += t;
  }
  if (lane < NB) bof[g * NB + lane] = s - v;
}

__global__ __launch_bounds__(1024) void k_scan3(int* __restrict__ off,
                                                const int* __restrict__ bof) {
  int g = blockIdx.y;
  int add = bof[g * NB + blockIdx.x];
  int i = blockIdx.x * 4096 + (int)threadIdx.x * 4;
  int* o = off + (size_t)g * NR;
  if (i + 3 < NR) {
    int4 v = *(const int4*)&o[i];
    v.x += add; v.y += add; v.z += add; v.w += add;
    *(int4*)&o[i] = v;
  } else {
    for (int j = i; j < NR; ++j) o[j] += add;
  }
}

// ---- scatter src ids; DESTROYS off: post-scatter off[s] = end of segment s ----
__global__ void k_scatter(const int* __restrict__ ei, const int* __restrict__ et,
                          int* __restrict__ off, int* __restrict__ ssrc) {
  int e = blockIdx.x * blockDim.x + threadIdx.x;
  int g = e >= EE;
  int el = e - g * EE;
  int s = ei[(size_t)g * 2 * EE + el];
  int d = ei[(size_t)g * 2 * EE + EE + el];
  int t = et[(size_t)g * EE + el];
  int pos = atomicAdd(&off[(size_t)g * NR + d * RR + t], 1);
  ssrc[(size_t)g * EE + pos] = s;
}

// ---- fp32 x -> bf16, both graphs, into per-graph NN*256-strided slots ----
__global__ void k_cvt(const float* __restrict__ x, unsigned short* __restrict__ hX) {
  int i = (blockIdx.x * blockDim.x + threadIdx.x) * 4;
  if (i >= 2 * NN * 128) return;
  int g = i >= NN * 128;
  int il = i - g * NN * 128;
  float4 v = *(const float4*)&x[i];
  ushort4 o;
  o.x = f2bf(v.x); o.y = f2bf(v.y); o.z = f2bf(v.z); o.w = f2bf(v.w);
  *(ushort4*)&hX[(size_t)g * NN * 256 + il] = o;
}

// ---- fragment-ordered bf16 weight panel:
// btf[((s*(Cout/16)+fr)*2+kk)*512 + lane*8 + j] = BT[co][k]
//   co = fr*16 + (lane&15);  k = s*64 + kk*32 + (lane>>4)*8 + j  (r=8 -> root)
__global__ void k_btf(const float* __restrict__ W, const float* __restrict__ root,
                      unsigned short* __restrict__ btf, int Cin, int Cout,
                      int Ktot) {
  int idx = blockIdx.x * blockDim.x + threadIdx.x;
  if (idx >= Cout * Ktot) return;
  int j = idx & 7;
  int lane = (idx >> 3) & 63;
  int kk = (idx >> 9) & 1;
  int t = idx >> 10;  // s*(Cout/16) + fr
  int fr = t % (Cout / 16);
  int s = t / (Cout / 16);
  int co = fr * 16 + (lane & 15);
  int k = s * 64 + kk * 32 + (lane >> 4) * 8 + j;
  int r = k / Cin, ci = k - r * Cin;
  float v = (r < RR) ? W[((size_t)r * Cin + ci) * Cout + co]
                     : root[(size_t)ci * Cout + co];
  btf[idx] = f2bf(v);
}

// coalesced B-frag load for step s: per (kk,f) 64 lanes read contiguous 1KB
#define LOADB(bb, s)                                                           \
  _Pragma("unroll") for (int kk = 0; kk < 2; ++kk)                             \
      _Pragma("unroll") for (int f = 0; f < 4; ++f) bb[kk][f] =                \
          *(const s16x8*)(btl +                                                \
                          (size_t)(((s) * (COUT / 16) + wn16 + f) * 2 + kk) *  \
                              512);

// MFMA over sub-tile j of As with B regs bb
#define MFMA_STEP_C(j, bb)                                                     \
  do {                                                                         \
    _Pragma("unroll") for (int kk = 0; kk < 2; ++kk) {                         \
      s16x8 a[MF];                                                             \
      _Pragma("unroll") for (int f = 0; f < MF; ++f) {                         \
        int row = wm + f * 16 + (lane & 15);                                   \
        int colb = kk * 64 + (lane >> 4) * 16;                                 \
        a[f] = *(const s16x8*)(As + (j)*ASTR + row * 128 +                     \
                               (colb ^ ((row & 7) << 4)));                     \
      }                                                                        \
      _Pragma("unroll") for (int fm = 0; fm < MF; ++fm)                        \
          _Pragma("unroll") for (int fn = 0; fn < 4; ++fn)                     \
              acc[fm][fn] = __builtin_amdgcn_mfma_f32_16x16x32_bf16(           \
                  a[fm], bb[kk][fn], acc[fm][fn], 0, 0, 0);                    \
    }                                                                          \
  } while (0)

// accumulate one uint4 (8 bf16) into packed float2 banks (v_pk_add_f32):
// 3 VALU per 2 elements (shift, mask, pk-add)
#define ACC4(u)                                                                \
  {                                                                            \
    fa2[c][0] += bf2x2((u).x);                                                 \
    fa2[c][1] += bf2x2((u).y);                                                 \
    fa2[c][2] += bf2x2((u).z);                                                 \
    fa2[c][3] += bf2x2((u).w);                                                 \
  }

// ---- fused gather+GEMM, 32-row x COUT tile, RPP relations per phase with
// RPP*CH == 8 sub-tiles (CIN=128: 4 rel/phase, CIN=256: 2 rel/phase; same
// 33KB LDS), packed-f32 walk accumulation, B in registers ----
template <int CIN, int COUT, bool OUTF32>
__global__ __launch_bounds__(256) void k_fused(
    const int* __restrict__ ssrc, const int* __restrict__ off,
    const unsigned short* __restrict__ h, const unsigned short* __restrict__ btf,
    const float* __restrict__ bias, void* __restrict__ outp) {
  constexpr int KTOT = (RR + 1) * CIN;
  constexpr int NS = KTOT / 64;    // flat K-steps (18 or 36)
  constexpr int CH = CIN / 64;     // sub-tiles per relation (2 or 4)
  constexpr int RPP = 8 / CH;      // relations per phase (4 or 2)
  constexpr int NPH = RR / RPP;    // phases (2 or 4)
  constexpr int CPT = CIN / 8;     // cols per thread in walk (16 or 32)
  constexpr int NCH = CPT / 8;     // 16B chunks per thread (2 or 4)
  constexpr int NWN = COUT / 64;   // n-waves (4 or 2)
  constexpr int MW = 4 / NWN;      // m-waves (1 or 2)
  constexpr int WR = 32 / MW;      // rows per wave (32 or 16)
  constexpr int MF = WR / 16;      // m-frags per wave (2 or 1)
  constexpr int ASTR = 4112;       // padded sub-tile stride (4096+16, not %128)
  constexpr int SH = (CIN == 256) ? 9 : 8;  // src -> h-row byte offset shift
  static_assert(RPP * CH == 8, "phase holds 8 sub-tiles");
  __shared__ char As[8 * ASTR];    // one phase's sub-tiles
  __shared__ int offs[32][9];      // per-row segment boundaries (start + 8 ends)
  __shared__ int sseg[SCAP];       // this block's edge window (BYTE offsets)
  const int tid = threadIdx.x, lane = tid & 63, wave = tid >> 6;
  const int wn = (wave % NWN) * 64;
  const int wn16 = wn >> 4;
  const int wm = (wave / NWN) * WR;
  const int m0 = blockIdx.x * 32;  // NN == 625*32, no clamps needed
  const int g = blockIdx.z;
  ssrc += (size_t)g * EE;
  off += (size_t)g * NR;
  h += (size_t)g * NN * 256;

  for (int idx = tid; idx < 32 * 9; idx += 256) {
    int row = idx / 9, j = idx - row * 9;
    int seg0 = (m0 + row) * RR;
    offs[row][j] = (j == 0) ? (seg0 == 0 ? 0 : off[seg0 - 1]) : off[seg0 + j - 1];
  }
  const int segA = m0 * RR;
  const int ebase = (segA == 0) ? 0 : off[segA - 1];
  const int eend = off[(m0 + 32) * RR - 1];
  const int cntE = eend - ebase;
  const bool inl = cntE <= SCAP;
  if (inl)
    for (int i = tid; i < cntE; i += 256) sseg[i] = ssrc[ebase + i] << SH;
  __syncthreads();

  f32x4 acc[MF][4] = {};
  const int arow = tid >> 3;              // this thread's A row (0..31)
  const int q = tid & 7;                  // 8 threads/row, CPT cols each
  const int swzA = (arow & 7) << 4;
  const char* hqB = (const char*)h + (size_t)q * CPT * 2;
  const unsigned short* btl = btf + lane * 8;

  // walk relation r's segment; write means into sub-tile base (r%RPP)*CH
  auto produce = [&](int r) {
    f32x2 fa2[NCH][4];
#pragma unroll
    for (int c = 0; c < NCH; ++c)
#pragma unroll
      for (int w = 0; w < 4; ++w) fa2[c][w] = (f32x2)(0.f);
    const int o0 = offs[arow][r], o1 = offs[arow][r + 1];
    if (inl) {  // hot path: edge ids (pre-shifted byte offsets) in LDS
      int e = o0 - ebase;
      const int e1 = o1 - ebase;
      for (; e + 1 < e1; e += 2) {
        const unsigned short* pa = (const unsigned short*)(hqB + sseg[e]);
        const unsigned short* pb = (const unsigned short*)(hqB + sseg[e + 1]);
#pragma unroll
        for (int c = 0; c < NCH; ++c) {
          uint4 ua = *(const uint4*)(pa + c * 8);
          uint4 ub = *(const uint4*)(pb + c * 8);
          ACC4(ua);
          ACC4(ub);
        }
      }
      if (e < e1) {
        const unsigned short* pa = (const unsigned short*)(hqB + sseg[e]);
#pragma unroll
        for (int c = 0; c < NCH; ++c) {
          uint4 ua = *(const uint4*)(pa + c * 8);
          ACC4(ua);
        }
      }
    } else {  // cold fallback: window overflow, read ids from global
      for (int e = o0; e < o1; ++e) {
        const unsigned short* pa = (const unsigned short*)(hqB + (ssrc[e] << SH));
#pragma unroll
        for (int c = 0; c < NCH; ++c) {
          uint4 ua = *(const uint4*)(pa + c * 8);
          ACC4(ua);
        }
      }
    }
    float inv = 1.0f / fmaxf((float)(o1 - o0), 1.0f);
    char* half = As + (r % RPP) * (CH * ASTR);
#pragma unroll
    for (int c = 0; c < NCH; ++c) {
      s16x8 mbv;
#pragma unroll
      for (int w = 0; w < 4; ++w) {
        mbv[2 * w] = (short)f2bf(fa2[c][w].x * inv);
        mbv[2 * w + 1] = (short)f2bf(fa2[c][w].y * inv);
      }
      int colb = (q * CPT + c * 8) * 2;  // byte col in full CIN row
      int ct = colb >> 7;                // sub-tile index within relation
      int wb = colb & 127;               // byte within 128-B window
      *(s16x8*)(half + ct * ASTR + arow * 128 + (wb ^ swzA)) = mbv;
    }
  };

  // root term: stage h rows into sub-tiles 0..CH-1 via global_load_lds
  auto root_stage = [&]() {
#pragma unroll
    for (int i = 0; i < CH; ++i) {
      int o = i * ASTR + wave * 1024;  // wave-uniform LDS base
      int ob = wave * 1024 + lane * 16;
      int row = (ob >> 7) & 31;
      int wb = ob & 127;
      gload_lds16((const char*)h + ((size_t)(m0 + row) * CIN + i * 64) * 2 +
                      (wb ^ ((row & 7) << 4)),
                  As + o);
    }
  };

  s16x8 bc[2][4], bn[2][4];
  LOADB(bc, 0);
#pragma unroll
  for (int r0 = 0; r0 < RPP; ++r0) produce(r0);
  __syncthreads();

  for (int p = 0; p < NPH; ++p) {
#pragma unroll
    for (int j = 0; j < 8; j += 2) {  // parity ping-pong, no copies
      int s = p * 8 + j;
      LOADB(bn, s + 1);               // s+1 < NS always (root steps follow)
      __builtin_amdgcn_s_setprio(1);
      MFMA_STEP_C(j, bc);
      __builtin_amdgcn_s_setprio(0);
      LOADB(bc, s + 2);               // s+2 <= NPH*8 <= NS-CH, valid
      __builtin_amdgcn_s_setprio(1);
      MFMA_STEP_C(j + 1, bn);
      __builtin_amdgcn_s_setprio(0);
    }
    __syncthreads();  // all waves done reading As
    if (p < NPH - 1) {
#pragma unroll
      for (int r0 = 0; r0 < RPP; ++r0) produce((p + 1) * RPP + r0);
    } else {
      root_stage();
    }
    __syncthreads();  // As writes visible
  }
  // root MFMA phase (sub-tiles 0..CH-1, flat steps RR*CH..NS-1)
#pragma unroll
  for (int c = 0; c < CH; c += 2) {
    int s = RR * CH + c;
    if (s + 1 < NS) { LOADB(bn, s + 1); }
    __builtin_amdgcn_s_setprio(1);
    MFMA_STEP_C(c, bc);
    __builtin_amdgcn_s_setprio(0);
    if (s + 2 < NS) { LOADB(bc, s + 2); }
    __builtin_amdgcn_s_setprio(1);
    MFMA_STEP_C(c + 1, bn);
    __builtin_amdgcn_s_setprio(0);
  }

  // ---- epilogue: bias + LeakyReLU ----
#pragma unroll
  for (int fm = 0; fm < MF; ++fm) {
    int rbase = m0 + wm + fm * 16 + (lane >> 4) * 4;
#pragma unroll
    for (int fn = 0; fn < 4; ++fn) {
      int col = wn + fn * 16 + (lane & 15);
      float bv = bias[col];
#pragma unroll
      for (int v = 0; v < 4; ++v) {
        int row = rbase + v;
        float xv = acc[fm][fn][v] + bv;
        xv = xv > 0.f ? xv : 0.2f * xv;
        if constexpr (OUTF32)
          ((float*)outp)[(size_t)g * NN * COUT + (size_t)row * COUT + col] = xv;
        else
          ((unsigned short*)outp)[(size_t)g * NN * 256 + (size_t)row * COUT +
                                  col] = f2bf(xv);
      }
    }
  }
}

extern "C" void kernel_launch(void* const* d_in, const int* in_sizes, int n_in,
                              void* d_out, int out_size, void* d_ws, size_t ws_size,
                              hipStream_t stream) {
  const float* x  = (const float*)d_in[0];
  const int* ei   = (const int*)d_in[1];
  const int* etp  = (const int*)d_in[2];
  const float* W0 = (const float*)d_in[3];
  const float* r0 = (const float*)d_in[4];
  const float* b0 = (const float*)d_in[5];
  const float* W1 = (const float*)d_in[6];
  const float* r1 = (const float*)d_in[7];
  const float* b1 = (const float*)d_in[8];
  const float* W2 = (const float*)d_in[9];
  const float* r2 = (const float*)d_in[10];
  const float* b2 = (const float*)d_in[11];

  char* p = (char*)d_ws;
  unsigned short* hX  = (unsigned short*)p; p += (size_t)2 * NN * 256 * 2;
  unsigned short* h_a = (unsigned short*)p; p += (size_t)2 * NN * 256 * 2;
  int* cnt  = (int*)p; p += (size_t)2 * NR * 4;
  int* off  = (int*)p; p += (size_t)2 * NR * 4;
  int* btot = (int*)p; p += (size_t)2 * NB * 4;
  int* bof  = (int*)p; p += (size_t)2 * NB * 4;
  int* ssrc = (int*)p; p += (size_t)2 * EE * 4;
  unsigned short* bt0 = (unsigned short*)p; p += (size_t)256 * 1152 * 2;
  unsigned short* bt1 = (unsigned short*)p; p += (size_t)256 * 2304 * 2;
  unsigned short* bt2 = (unsigned short*)p; p += (size_t)128 * 2304 * 2;

  // fragment-ordered weight panels (graph-independent)
  k_btf<<<(256 * 1152 + 255) / 256, 256, 0, stream>>>(W0, r0, bt0, 128, 256, 1152);
  k_btf<<<(256 * 2304 + 255) / 256, 256, 0, stream>>>(W1, r1, bt1, 256, 256, 2304);
  k_btf<<<(128 * 2304 + 255) / 256, 256, 0, stream>>>(W2, r2, bt2, 256, 128, 2304);

  // edge sort (both graphs batched)
  (void)hipMemsetAsync(cnt, 0, (size_t)2 * NR * 4, stream);
  k_count<<<2 * EE / 256, 256, 0, stream>>>(ei, etp, cnt);
  k_scan1<<<dim3(NB, 2), 1024, 0, stream>>>(cnt, off, btot);
  k_scan2<<<1, 128, 0, stream>>>(btot, bof);
  k_scan3<<<dim3(NB, 2), 1024, 0, stream>>>(off, bof);
  k_cvt<<<2 * NN * 128 / 4 / 256, 256, 0, stream>>>(x, hX);
  k_scatter<<<2 * EE / 256, 256, 0, stream>>>(ei, etp, off, ssrc);

  // layer 0: 128 -> 256 (fused gather+GEMM)
  k_fused<128, 256, false><<<dim3(625, 1, 2), 256, 0, stream>>>(
      ssrc, off, hX, bt0, b0, h_a);
  // layer 1: 256 -> 256
  k_fused<256, 256, false><<<dim3(625, 1, 2), 256, 0, stream>>>(
      ssrc, off, h_a, bt1, b1, hX);
  // layer 2: 256 -> 128
  k_fused<256, 128, true><<<dim3(625, 1, 2), 256, 0, stream>>>(
      ssrc, off, hX, bt2, b2, d_out);
}